// Round 18
// baseline (193.829 us; speedup 1.0000x reference)
//
#include <hip/hip_runtime.h>
#include <math.h>

#define GDIM 152
#define NA 3
#define GG (GDIM * GDIM)        // 23104
#define EXP_CLAMP 1000.0f
#define NTHREADS 64             // single-wave blocks
#define TILE 256                // cells per tile = 4 * NTHREADS
#define GSTRIDE (TILE + 1)      // 257 float4s between group planes
#define TILES_TOTAL 8664        // 32*3*GG / 256, exact
#define NTPB 4                  // tiles per persistent block
#define NBLK (TILES_TOTAL / NTPB)   // 2166; ~8.5 blocks/CU resident (LDS cap 12)
// NBLK*TILE = 554,496 cells = 24*GG exactly -> per-thread pos/gy/gx0/a are
// loop-invariant (t2 += 24, 24%3==0); both pointers advance by one constant.
#define ISTEP ((size_t)24 * 12 * (GG / 4))  // input step in float4 units
#define OSTEP ((size_t)NBLK * TILE * 3)     // output step in float4 units

typedef float floatx4 __attribute__((ext_vector_type(4)));

__device__ __forceinline__ float sigmoidf(float v) {
    return 1.0f / (1.0f + __expf(-v));
}

// XOR swizzle on float4 entry index (bijective on [0,256)).
__device__ __forceinline__ int swz(int e) { return e ^ ((e >> 3) & 7); }

// BARRIER-FREE persistent pipeline. Single-wave blocks never needed
// __syncthreads for correctness (LDS write->read ordering within one wave is
// enforced by compiler-inserted lgkmcnt waits on aliasing DS ops); the barrier
// only contributed a vmcnt(0) drain that force-completed the next tile's
// prefetch loads — which is why every pipelined variant showed VGPR~68 and no
// speedup (the compiler sank loads it knew would be drained immediately).
// With barriers gone + __launch_bounds__(64,1) (no reg-pressure motive) +
// sched_barrier(0) pins (no scheduler sinking), tile i+2's 12 dwordx4 loads
// genuinely fly while tile i computes.
__global__ __launch_bounds__(NTHREADS, 1) void yolo_decode_nobar(
    const float* __restrict__ x,
    const float* __restrict__ anchors,
    const int* __restrict__ img_size_p,
    float* __restrict__ out)
{
    __shared__ floatx4 sh[3 * GSTRIDE];   // 12,336 B

    const int t = threadIdx.x;
    const int tilebase = blockIdx.x * TILE;

    const float stride = (float)(*img_size_p) / (float)GDIM;  // 4.0
    const float inv_s = 1.0f / stride;

    // Loop-invariant per-thread context (cells tilebase+4t..+3, same plane/row)
    const int cbase = tilebase + 4 * t;
    const unsigned t2 = (unsigned)cbase / (unsigned)GG;  // b*NA + a
    const int pos = cbase - (int)t2 * GG;
    const int gy  = pos / GDIM;
    const int gx0 = pos - gy * GDIM;
    const int a   = (int)(t2 % 3u);
    const float gyf = (float)gy;

    const int PS = GG / 4;
    const floatx4* ip = (const floatx4*)x + (size_t)(t2 * 12u) * PS + (pos >> 2);
    floatx4* op = (floatx4*)out + (size_t)tilebase * 3;

    const float ah = anchors[a * 5 + 0] * inv_s * stride;  // matches reference rounding
    const float aw = anchors[a * 5 + 1] * inv_s * stride;
    const float al = anchors[a * 5 + 2] * inv_s * stride;

#define LOAD12(R)                                                        \
    do {                                                                 \
        _Pragma("unroll")                                                \
        for (int k = 0; k < 12; ++k) (R)[k] = ip[k * PS];                \
        ip += ISTEP;                                                     \
    } while (0)

#define PROCJ(R, J)                                                      \
    do {                                                                 \
        floatx4 o0, o1, o2;                                              \
        o0.x = (sigmoidf(R[0][J]) + (float)(gx0 + (J))) * stride;        \
        o0.y = (sigmoidf(R[1][J]) + gyf) * stride;                       \
        o0.z = sigmoidf(R[2][J]);                                        \
        o0.w = fminf(__expf(R[3][J]), EXP_CLAMP) * ah;                   \
        o1.x = fminf(__expf(R[4][J]), EXP_CLAMP) * aw;                   \
        o1.y = fminf(__expf(R[5][J]), EXP_CLAMP) * al;                   \
        o1.z = R[6][J];                                                  \
        o1.w = R[7][J];                                                  \
        o2.x = sigmoidf(R[8][J]);                                        \
        o2.y = sigmoidf(R[9][J]);                                        \
        o2.z = sigmoidf(R[10][J]);                                       \
        o2.w = sigmoidf(R[11][J]);                                       \
        int e = swz(4 * t + (J));                                        \
        sh[0 * GSTRIDE + e] = o0;                                        \
        sh[1 * GSTRIDE + e] = o1;                                        \
        sh[2 * GSTRIDE + e] = o2;                                        \
    } while (0)

// LDS -> lane-contiguous plain stores. No barrier: the compiler orders the
// aliasing ds_write->ds_read (and the following tile's ds_write WAR) via
// lgkmcnt waits; vmcnt is never force-drained.
#define STORE12                                                          \
    do {                                                                 \
        _Pragma("unroll")                                                \
        for (int k2 = 0; k2 < 12; ++k2) {                                \
            int F = t + NTHREADS * k2;                                   \
            unsigned cell = (unsigned)F / 3u;                            \
            int g = F - (int)cell * 3;                                   \
            op[F] = sh[g * GSTRIDE + swz((int)cell)];                    \
        }                                                                \
        op += OSTEP;                                                     \
    } while (0)

    floatx4 ra[12], rb[12];
    LOAD12(ra);                                    // tile 0
    LOAD12(rb);                                    // tile 1 (24 loads in flight)
    __builtin_amdgcn_sched_barrier(0);             // pin prologue loads here

    // tile 0
    PROCJ(ra, 0); PROCJ(ra, 1); PROCJ(ra, 2); PROCJ(ra, 3);
    LOAD12(ra);                                    // tile 2 prefetch
    __builtin_amdgcn_sched_barrier(0);             // no sinking past stores
    STORE12;

    // tile 1
    PROCJ(rb, 0); PROCJ(rb, 1); PROCJ(rb, 2); PROCJ(rb, 3);
    LOAD12(rb);                                    // tile 3 prefetch
    __builtin_amdgcn_sched_barrier(0);
    STORE12;

    // tile 2
    PROCJ(ra, 0); PROCJ(ra, 1); PROCJ(ra, 2); PROCJ(ra, 3);
    STORE12;

    // tile 3
    PROCJ(rb, 0); PROCJ(rb, 1); PROCJ(rb, 2); PROCJ(rb, 3);
    STORE12;

#undef LOAD12
#undef PROCJ
#undef STORE12
}

extern "C" void kernel_launch(void* const* d_in, const int* in_sizes, int n_in,
                              void* d_out, int out_size, void* d_ws, size_t ws_size,
                              hipStream_t stream) {
    const float* x        = (const float*)d_in[0];
    const float* anchors  = (const float*)d_in[1];
    const int*   img_size = (const int*)d_in[2];
    float*       out      = (float*)d_out;

    yolo_decode_nobar<<<NBLK, NTHREADS, 0, stream>>>(x, anchors, img_size, out);
}